// Round 8
// baseline (262.795 us; speedup 1.0000x reference)
//
#include <hip/hip_runtime.h>

// LocalGlobalCausalSelfAttention — R8: GEMMs switched 16x16x32 -> 32x32x16
// (2382 vs 2075 TF ubench; half the MFMA instruction count per FLOP).
// Same 128^2 tile / BK=32 / 2-phase dbuf / chunk-swizzle structure as R7.
// Attn: per-lane partial l (sum-reduce deferred to epilogue; alpha is
// group-uniform) — halves the per-pass shfl count. Otherwise unchanged.

#define NHD   16
#define CEMB  1024
#define C3    3072
#define DH    64
#define WIN   256
#define NGLB  4
#define TB    256

typedef __attribute__((ext_vector_type(8)))  short  short8v;
typedef __attribute__((ext_vector_type(4)))  float  f32x4;
typedef __attribute__((ext_vector_type(16))) float  f32x16;
typedef __attribute__((ext_vector_type(8)))  unsigned short ushort8v;

__device__ __forceinline__ unsigned short f2bf_rn(float f) {
    unsigned int u = __float_as_uint(f);
    u += 0x7fffu + ((u >> 16) & 1u);
    return (unsigned short)(u >> 16);
}
__device__ __forceinline__ float bf2f(unsigned short h) {
    return __uint_as_float(((unsigned int)h) << 16);
}

// ---------- fused fp32 -> (bf16 hi, bf16 lo) split for x, w_attn, w_proj ----------
__global__ __launch_bounds__(TB)
void split3_kernel(const float* __restrict__ x, const float* __restrict__ wa,
                   const float* __restrict__ wp,
                   unsigned short* __restrict__ xh, unsigned short* __restrict__ xl,
                   unsigned short* __restrict__ wah, unsigned short* __restrict__ wal,
                   unsigned short* __restrict__ wph, unsigned short* __restrict__ wpl,
                   int n8x, int n8a, int n8p) {
    const int total = n8x + n8a + n8p;
    for (int i = blockIdx.x * blockDim.x + threadIdx.x; i < total;
         i += gridDim.x * blockDim.x) {
        const float* src; unsigned short *ph, *pl; int j;
        if (i < n8x)            { src = x;  ph = xh;  pl = xl;  j = i; }
        else if (i < n8x + n8a) { src = wa; ph = wah; pl = wal; j = i - n8x; }
        else                    { src = wp; ph = wph; pl = wpl; j = i - n8x - n8a; }
        float4 v0 = ((const float4*)src)[2 * j];
        float4 v1 = ((const float4*)src)[2 * j + 1];
        float f[8] = {v0.x, v0.y, v0.z, v0.w, v1.x, v1.y, v1.z, v1.w};
        ushort8v h, l;
#pragma unroll
        for (int e = 0; e < 8; ++e) {
            unsigned short hb = f2bf_rn(f[e]);
            h[e] = hb;
            l[e] = f2bf_rn(f[e] - bf2f(hb));
        }
        *(ushort8v*)&ph[(size_t)j * 8] = h;
        *(ushort8v*)&pl[(size_t)j * 8] = l;
    }
}

// ---------- split-bf16 MFMA GEMM: C[M,N] = A[M,K] * B[N,K]^T ----------
// 128x128 tile, BK=32, 4 waves (2x2), wave tile 64x64 = 2x2 frags of
// mfma_f32_32x32x16_bf16; 3-term split => 24 MFMA/wave/K-step.
// Double-buffered LDS (2 x 4 planes x 8KB = 64KB), 2-phase: STAGE(t+1)
// before compute(t), one __syncthreads per K-step.
// LDS chunk swizzle (16B chunks, slot = c ^ ((row>>1)&3)): staging writes
// linear dest + inverse-permuted global source (rule #21); reads use the
// same XOR. 32x32 frag layouts: A/B row|col = lane&31, k = (lane>>5)*8+i
// (analog of the validated 16x16x32 layout); C/D col = lane&31,
// row = (reg&3)+8*(reg>>2)+4*(lane>>5)  [HW-verified m74/m101].
__device__ __forceinline__ void g2l16(const void* g, void* l) {
    __builtin_amdgcn_global_load_lds(
        (const __attribute__((address_space(1))) void*)g,
        (__attribute__((address_space(3))) void*)l, 16, 0, 0);
}

// OUTMODE 0: f32 C.  OUTMODE 1: hi/lo bf16 C, cols < CEMB scaled by 1/8 (Q).
template<int OUTMODE>
__global__ __launch_bounds__(TB)
void gemm_split_mfma_kernel(const unsigned short* __restrict__ Ah,
                            const unsigned short* __restrict__ Al,
                            const unsigned short* __restrict__ Bh,
                            const unsigned short* __restrict__ Bl,
                            float* __restrict__ Cf,
                            unsigned short* __restrict__ Ch,
                            unsigned short* __restrict__ Cl,
                            int M, int N, int K) {
    __shared__ unsigned short lds[2][4][128 * 32];   // dbuf x {Ah,Al,Bh,Bl}

    const int tid  = threadIdx.x;
    const int wave = tid >> 6;
    const int lane = tid & 63;
    const int nbn  = N >> 7;
    const int mb   = blockIdx.x / nbn;
    const int nb   = blockIdx.x % nbn;

    // staging: slot c in {0,1}: rows (c*4+wave)*16 + lane/4; source chunk swizzled
    const int row0 = (wave)     * 16 + (lane >> 2);
    const int row1 = (wave + 4) * 16 + (lane >> 2);
    const int koff = (((lane & 3) ^ ((lane >> 3) & 3)) << 3);   // inverse-swz source
    const size_t aoff0 = (size_t)(mb * 128 + row0) * K + koff;
    const size_t aoff1 = (size_t)(mb * 128 + row1) * K + koff;
    const size_t boff0 = (size_t)(nb * 128 + row0) * K + koff;
    const size_t boff1 = (size_t)(nb * 128 + row1) * K + koff;
    const int l0 = wave * 512;          // wave-uniform LDS bases (ushort idx)
    const int l1 = (wave + 4) * 512;

    const int wr  = wave >> 1, wc = wave & 1;
    const int l31 = lane & 31;
    const int l5  = lane >> 5;                   // k-half selector within chunk pair
    const int sel = (l31 >> 1) & 3;              // read-side swizzle selector

    f32x16 acc[2][2];
#pragma unroll
    for (int m = 0; m < 2; ++m)
#pragma unroll
        for (int n = 0; n < 2; ++n)
#pragma unroll
            for (int r = 0; r < 16; ++r) acc[m][n][r] = 0.f;

    auto STAGE = [&](int bi, int kt) {
        g2l16(Ah + aoff0 + kt, &lds[bi][0][l0]);
        g2l16(Ah + aoff1 + kt, &lds[bi][0][l1]);
        g2l16(Al + aoff0 + kt, &lds[bi][1][l0]);
        g2l16(Al + aoff1 + kt, &lds[bi][1][l1]);
        g2l16(Bh + boff0 + kt, &lds[bi][2][l0]);
        g2l16(Bh + boff1 + kt, &lds[bi][2][l1]);
        g2l16(Bl + boff0 + kt, &lds[bi][3][l0]);
        g2l16(Bl + boff1 + kt, &lds[bi][3][l1]);
    };

    STAGE(0, 0);
    __syncthreads();                     // drain vmcnt(0): buf0 ready
    int cur = 0;

    for (int kt = 0; kt < K; kt += 32) {
        if (kt + 32 < K) STAGE(cur ^ 1, kt + 32);   // in flight across compute

#pragma unroll
        for (int kk = 0; kk < 2; ++kk) {            // two k=16 halves of BK=32
            const int c0   = kk * 2 + l5;           // logical 16B chunk
            short8v ah[2], al[2], bh[2], bl[2];
#pragma unroll
            for (int m = 0; m < 2; ++m) {
                const int row = wr * 64 + m * 32 + l31;
                const int r   = row * 32 + ((c0 ^ sel) << 3);
                ah[m] = *(const short8v*)&lds[cur][0][r];
                al[m] = *(const short8v*)&lds[cur][1][r];
            }
#pragma unroll
            for (int n = 0; n < 2; ++n) {
                const int row = wc * 64 + n * 32 + l31;
                const int r   = row * 32 + ((c0 ^ sel) << 3);
                bh[n] = *(const short8v*)&lds[cur][2][r];
                bl[n] = *(const short8v*)&lds[cur][3][r];
            }
#pragma unroll
            for (int m = 0; m < 2; ++m)
#pragma unroll
                for (int n = 0; n < 2; ++n) {
                    acc[m][n] = __builtin_amdgcn_mfma_f32_32x32x16_bf16(
                        ah[m], bh[n], acc[m][n], 0, 0, 0);
                    acc[m][n] = __builtin_amdgcn_mfma_f32_32x32x16_bf16(
                        ah[m], bl[n], acc[m][n], 0, 0, 0);
                    acc[m][n] = __builtin_amdgcn_mfma_f32_32x32x16_bf16(
                        al[m], bh[n], acc[m][n], 0, 0, 0);
                }
        }

        __syncthreads();   // vmcnt(0)+lgkmcnt(0)+barrier: next buf staged,
        cur ^= 1;          // this buf free for overwrite next iteration
    }

    // C write: 32x32 C/D layout col=lane&31, row=(reg&3)+8*(reg>>2)+4*(lane>>5)
#pragma unroll
    for (int m = 0; m < 2; ++m)
#pragma unroll
        for (int n = 0; n < 2; ++n) {
#pragma unroll
            for (int r = 0; r < 16; ++r) {
                const int row = mb * 128 + wr * 64 + m * 32
                              + (r & 3) + 8 * (r >> 2) + 4 * l5;
                const int col = nb * 128 + wc * 64 + n * 32 + l31;
                if constexpr (OUTMODE == 0) {
                    Cf[(size_t)row * N + col] = acc[m][n][r];
                } else {
                    float v = acc[m][n][r];
                    if (col < CEMB) v *= 0.125f;   // pre-scale Q by 1/sqrt(D)
                    unsigned short hb = f2bf_rn(v);
                    Ch[(size_t)row * N + col] = hb;
                    Cl[(size_t)row * N + col] = f2bf_rn(v - bf2f(hb));
                }
            }
        }
}

// ---------- fused attention, split-bf16 MFMA ----------
// Same structure as R5/R7 (passing); change: lrow holds per-lane PARTIAL
// sums (alpha is uniform across the 16-lane row group), reduced once in
// the epilogue — deletes the per-pass 4-step sum shfl reduce.
__global__ __launch_bounds__(TB)
void attn_mfma_kernel(const unsigned short* __restrict__ qkvh,
                      const unsigned short* __restrict__ qkvl,
                      unsigned short* __restrict__ yh,
                      unsigned short* __restrict__ yl, int T) {
    __shared__ unsigned short Kh[4096], Kl[4096], VTh[4096], VTl[4096],
                              Ph[4096], Pl[4096];

    const int tid = threadIdx.x;
    const int wv  = tid >> 6, ln = tid & 63;
    const int g   = ln >> 4, fr = ln & 15;
    const int nq  = T >> 6;
    const int qt  = blockIdx.x % nq;
    const int bh  = blockIdx.x / nq;
    const int h   = bh % NHD, b = bh / NHD;
    const int qs  = qt << 6;
    const size_t bT = (size_t)b * T;

    const size_t qbase = (bT + qs + wv * 16 + fr) * C3 + h * DH;
    short8v qfh[2], qfl[2];
    qfh[0] = *(const short8v*)(qkvh + qbase + g * 8);
    qfh[1] = *(const short8v*)(qkvh + qbase + 32 + g * 8);
    qfl[0] = *(const short8v*)(qkvl + qbase + g * 8);
    qfl[1] = *(const short8v*)(qkvl + qbase + 32 + g * 8);

    float mrow[4], lrow[4];
    f32x4 acc_o[4];
#pragma unroll
    for (int r = 0; r < 4; ++r) { mrow[r] = -3.0e38f; lrow[r] = 0.f; }
#pragma unroll
    for (int j = 0; j < 4; ++j) acc_o[j] = (f32x4){0.f, 0.f, 0.f, 0.f};

    int kt_first = 0;
    const int wstart = qs - (WIN - 1);
    if (wstart > 0) kt_first = wstart >> 6;
    const int has_g = (kt_first > 0) ? 1 : 0;
    const int npass = qt - kt_first + 1 + has_g;

    const int srow = tid >> 2;
    const int sc   = tid & 3;
    const int kidx0 = srow * 64 + ((sc * 8)       ^ ((srow & 7) << 3));
    const int kidx1 = srow * 64 + (((sc + 4) * 8) ^ ((srow & 7) << 3));

    short8v kh0, kh1, kl0, kl1, vh0, vh1, vl0, vl1;
    auto load_tile = [&](int k0) {
        const size_t kb = (bT + k0 + srow) * C3 + CEMB + h * DH;
        kh0 = *(const short8v*)(qkvh + kb + sc * 8);
        kh1 = *(const short8v*)(qkvh + kb + (sc + 4) * 8);
        kl0 = *(const short8v*)(qkvl + kb + sc * 8);
        kl1 = *(const short8v*)(qkvl + kb + (sc + 4) * 8);
        const size_t vb = (bT + k0 + srow) * C3 + 2 * CEMB + h * DH + sc * 16;
        vh0 = *(const short8v*)(qkvh + vb);
        vh1 = *(const short8v*)(qkvh + vb + 8);
        vl0 = *(const short8v*)(qkvl + vb);
        vl1 = *(const short8v*)(qkvl + vb + 8);
    };
    auto kt_of = [&](int p) { return (has_g && p == 0) ? 0 : (kt_first + p - has_g); };

    load_tile(kt_of(0) * 64);

    for (int pass = 0; pass < npass; ++pass) {
        const int k0 = kt_of(pass) * 64;

        __syncthreads();
        *(short8v*)&Kh[kidx0] = kh0; *(short8v*)&Kh[kidx1] = kh1;
        *(short8v*)&Kl[kidx0] = kl0; *(short8v*)&Kl[kidx1] = kl1;
#pragma unroll
        for (int e = 0; e < 8; ++e) {
            const int d1 = sc * 16 + e, d2 = sc * 16 + 8 + e;
            const int i1 = d1 * 64 + (srow ^ (((d1 ^ (d1 >> 3)) & 7) << 3));
            const int i2 = d2 * 64 + (srow ^ (((d2 ^ (d2 >> 3)) & 7) << 3));
            VTh[i1] = (unsigned short)vh0[e]; VTh[i2] = (unsigned short)vh1[e];
            VTl[i1] = (unsigned short)vl0[e]; VTl[i2] = (unsigned short)vl1[e];
        }
        __syncthreads();

        if (pass + 1 < npass) load_tile(kt_of(pass + 1) * 64);

        f32x4 sa[4];
#pragma unroll
        for (int j = 0; j < 4; ++j) sa[j] = (f32x4){0.f, 0.f, 0.f, 0.f};
#pragma unroll
        for (int kk = 0; kk < 2; ++kk) {
#pragma unroll
            for (int j = 0; j < 4; ++j) {
                const int krow = j * 16 + fr;
                const int off  = (kk * 32 + g * 8) ^ ((krow & 7) << 3);
                short8v bhf = *(const short8v*)&Kh[krow * 64 + off];
                short8v blf = *(const short8v*)&Kl[krow * 64 + off];
                sa[j] = __builtin_amdgcn_mfma_f32_16x16x32_bf16(qfh[kk], bhf, sa[j], 0, 0, 0);
                sa[j] = __builtin_amdgcn_mfma_f32_16x16x32_bf16(qfh[kk], blf, sa[j], 0, 0, 0);
                sa[j] = __builtin_amdgcn_mfma_f32_16x16x32_bf16(qfl[kk], bhf, sa[j], 0, 0, 0);
            }
        }

#pragma unroll
        for (int r = 0; r < 4; ++r) {
            const int qloc = wv * 16 + g * 4 + r;
            const int qi   = qs + qloc;
            const int wlo  = qi - (WIN - 1);
            float mx = mrow[r];
            float s[4];
#pragma unroll
            for (int j = 0; j < 4; ++j) {
                const int kj = k0 + j * 16 + fr;
                const bool valid = (kj <= qi) && ((kj >= wlo) || (kj < NGLB));
                s[j] = valid ? sa[j][r] : -3.0e38f;
                mx = fmaxf(mx, s[j]);
            }
#pragma unroll
            for (int off = 1; off < 16; off <<= 1)
                mx = fmaxf(mx, __shfl_xor(mx, off, 64));
            const float alpha = __expf(mrow[r] - mx);
            float rsum = 0.f;
            unsigned short phv[4], plv[4];
#pragma unroll
            for (int j = 0; j < 4; ++j) {
                const float p = (s[j] > -1.0e38f) ? __expf(s[j] - mx) : 0.f;
                rsum += p;
                const unsigned short hb = f2bf_rn(p);
                phv[j] = hb; plv[j] = f2bf_rn(p - bf2f(hb));
            }
            lrow[r] = lrow[r] * alpha + rsum;    // per-lane partial (alpha uniform)
            mrow[r] = mx;
#pragma unroll
            for (int j = 0; j < 4; ++j) {
                acc_o[j][r] *= alpha;
                const int key = j * 16 + fr;
                const int idx = qloc * 64 + (key ^ ((qloc & 7) << 3));
                Ph[idx] = phv[j]; Pl[idx] = plv[j];
            }
        }

#pragma unroll
        for (int kk = 0; kk < 2; ++kk) {
            const int qloc = wv * 16 + fr;
            const int poff = (kk * 32 + g * 8) ^ ((qloc & 7) << 3);
            short8v pah = *(const short8v*)&Ph[qloc * 64 + poff];
            short8v pal = *(const short8v*)&Pl[qloc * 64 + poff];
#pragma unroll
            for (int j = 0; j < 4; ++j) {
                const int d   = j * 16 + fr;
                const int voff = (kk * 32 + g * 8) ^ (((d ^ (d >> 3)) & 7) << 3);
                short8v vfh = *(const short8v*)&VTh[d * 64 + voff];
                short8v vfl = *(const short8v*)&VTl[d * 64 + voff];
                acc_o[j] = __builtin_amdgcn_mfma_f32_16x16x32_bf16(pah, vfh, acc_o[j], 0, 0, 0);
                acc_o[j] = __builtin_amdgcn_mfma_f32_16x16x32_bf16(pah, vfl, acc_o[j], 0, 0, 0);
                acc_o[j] = __builtin_amdgcn_mfma_f32_16x16x32_bf16(pal, vfh, acc_o[j], 0, 0, 0);
            }
        }
    }

    // epilogue: deferred row-sum reduce (16-lane groups), normalize, write y
    float inv[4];
#pragma unroll
    for (int r = 0; r < 4; ++r) {
        float s = lrow[r];
#pragma unroll
        for (int off = 1; off < 16; off <<= 1)
            s += __shfl_xor(s, off, 64);
        inv[r] = 1.0f / s;
    }
#pragma unroll
    for (int j = 0; j < 4; ++j)
#pragma unroll
        for (int r = 0; r < 4; ++r) {
            const float o = acc_o[j][r] * inv[r];
            const size_t yi = (bT + qs + wv * 16 + g * 4 + r) * (size_t)CEMB
                            + h * DH + j * 16 + fr;
            const unsigned short hb = f2bf_rn(o);
            yh[yi] = hb; yl[yi] = f2bf_rn(o - bf2f(hb));
        }
}

// ===================== launcher =====================
extern "C" void kernel_launch(void* const* d_in, const int* in_sizes, int n_in,
                              void* d_out, int out_size, void* d_ws, size_t ws_size,
                              hipStream_t stream) {
    const float* x      = (const float*)d_in[0];
    const float* w_attn = (const float*)d_in[1];
    const float* w_proj = (const float*)d_in[2];
    float* out = (float*)d_out;

    const int T = 2048;
    const int B = in_sizes[0] / (T * CEMB);
    const int M = B * T;

    unsigned short* qkvh = (unsigned short*)d_ws;          // [M][3C]
    unsigned short* qkvl = qkvh + (size_t)M * C3;
    unsigned short* yh   = qkvl + (size_t)M * C3;          // [M][C]
    unsigned short* yl   = yh   + (size_t)M * CEMB;
    unsigned short* xh   = yl   + (size_t)M * CEMB;
    unsigned short* xl   = xh   + (size_t)M * CEMB;
    unsigned short* wah  = xl   + (size_t)M * CEMB;
    unsigned short* wal  = wah  + (size_t)C3 * CEMB;
    unsigned short* wph  = wal  + (size_t)C3 * CEMB;
    unsigned short* wpl  = wph  + (size_t)CEMB * CEMB;

    const int n8x = M * CEMB / 8;
    const int n8a = C3 * CEMB / 8;
    const int n8p = CEMB * CEMB / 8;
    split3_kernel<<<2048, TB, 0, stream>>>(x, w_attn, w_proj,
                                           xh, xl, wah, wal, wph, wpl,
                                           n8x, n8a, n8p);

    gemm_split_mfma_kernel<1><<<dim3((M / 128) * (C3 / 128)), dim3(TB), 0, stream>>>(
        xh, xl, wah, wal, nullptr, qkvh, qkvl, M, C3, CEMB);

    attn_mfma_kernel<<<dim3(B * NHD * (T / 64)), dim3(TB), 0, stream>>>(
        qkvh, qkvl, yh, yl, T);

    gemm_split_mfma_kernel<0><<<dim3((M / 128) * (CEMB / 128)), dim3(TB), 0, stream>>>(
        yh, yl, wph, wpl, out, nullptr, nullptr, M, CEMB, CEMB);
}

// Round 10
// 257.757 us; speedup vs baseline: 1.0195x; 1.0195x over previous
//
#include <hip/hip_runtime.h>

// LocalGlobalCausalSelfAttention — R9 resubmit (R9 bench was an acquisition
// timeout — infra, not a kernel verdict; code unchanged for a clean measure).
//  * GEMM shape reverted to 16x16x32 (R8's 32x32x16 was null-to-negative:
//    2-phase structure-bound, not MFMA-issue-bound; and it broke the swizzle
//    -> 6.3e6 conflicts). Template<OUTMODE, BN>.
//  * GEMM2 uses BN=64 tile: 512 blocks, 3 blocks/CU (48KB LDS) — fixes the
//    1-block/CU latency exposure at 256 blocks.
//  * Attn: per-lane partial l kept; s_setprio(1/0) around MFMA clusters
//    (3 co-resident blocks at different phases -> arbitration win, m191).

#define NHD   16
#define CEMB  1024
#define C3    3072
#define DH    64
#define WIN   256
#define NGLB  4
#define TB    256

typedef __attribute__((ext_vector_type(8))) short  short8v;
typedef __attribute__((ext_vector_type(4))) float  f32x4;
typedef __attribute__((ext_vector_type(8))) unsigned short ushort8v;

__device__ __forceinline__ unsigned short f2bf_rn(float f) {
    unsigned int u = __float_as_uint(f);
    u += 0x7fffu + ((u >> 16) & 1u);
    return (unsigned short)(u >> 16);
}
__device__ __forceinline__ float bf2f(unsigned short h) {
    return __uint_as_float(((unsigned int)h) << 16);
}

// ---------- fused fp32 -> (bf16 hi, bf16 lo) split for x, w_attn, w_proj ----------
__global__ __launch_bounds__(TB)
void split3_kernel(const float* __restrict__ x, const float* __restrict__ wa,
                   const float* __restrict__ wp,
                   unsigned short* __restrict__ xh, unsigned short* __restrict__ xl,
                   unsigned short* __restrict__ wah, unsigned short* __restrict__ wal,
                   unsigned short* __restrict__ wph, unsigned short* __restrict__ wpl,
                   int n8x, int n8a, int n8p) {
    const int total = n8x + n8a + n8p;
    for (int i = blockIdx.x * blockDim.x + threadIdx.x; i < total;
         i += gridDim.x * blockDim.x) {
        const float* src; unsigned short *ph, *pl; int j;
        if (i < n8x)            { src = x;  ph = xh;  pl = xl;  j = i; }
        else if (i < n8x + n8a) { src = wa; ph = wah; pl = wal; j = i - n8x; }
        else                    { src = wp; ph = wph; pl = wpl; j = i - n8x - n8a; }
        float4 v0 = ((const float4*)src)[2 * j];
        float4 v1 = ((const float4*)src)[2 * j + 1];
        float f[8] = {v0.x, v0.y, v0.z, v0.w, v1.x, v1.y, v1.z, v1.w};
        ushort8v h, l;
#pragma unroll
        for (int e = 0; e < 8; ++e) {
            unsigned short hb = f2bf_rn(f[e]);
            h[e] = hb;
            l[e] = f2bf_rn(f[e] - bf2f(hb));
        }
        *(ushort8v*)&ph[(size_t)j * 8] = h;
        *(ushort8v*)&pl[(size_t)j * 8] = l;
    }
}

// ---------- split-bf16 MFMA GEMM: C[M,N] = A[M,K] * B[N,K]^T ----------
// 128xBN tile, BK=32, 4 waves (2x2), mfma_f32_16x16x32_bf16, 3-term split.
// BN=128: wave tile 64x64, 4x4 frags, 48 MFMA/K-step (R7 config, measured
// 859 TF, 0 conflicts). BN=64: wave tile 64x32, 4x2 frags, 24 MFMA/K-step,
// 48KB LDS -> 3 blocks/CU (for the N=1024 proj GEMM).
// 2-phase dbuf: STAGE(t+1) before compute(t), one __syncthreads per K-step.
// LDS chunk swizzle (16B chunks, slot = c ^ ((row>>1)&3)): linear gload_lds
// dest + inverse-permuted global source + same XOR on ds_read (rule #21).
__device__ __forceinline__ void g2l16(const void* g, void* l) {
    __builtin_amdgcn_global_load_lds(
        (const __attribute__((address_space(1))) void*)g,
        (__attribute__((address_space(3))) void*)l, 16, 0, 0);
}

// OUTMODE 0: f32 C.  OUTMODE 1: hi/lo bf16 C, cols < CEMB scaled by 1/8 (Q).
template<int OUTMODE, int BN>
__global__ __launch_bounds__(TB)
void gemm_split_mfma_kernel(const unsigned short* __restrict__ Ah,
                            const unsigned short* __restrict__ Al,
                            const unsigned short* __restrict__ Bh,
                            const unsigned short* __restrict__ Bl,
                            float* __restrict__ Cf,
                            unsigned short* __restrict__ Ch,
                            unsigned short* __restrict__ Cl,
                            int M, int N, int K) {
    constexpr int NFR = BN / 32;                      // n-frags per wave: 4 or 2
    __shared__ unsigned short ldsA[2][2][128 * 32];   // dbuf x {hi,lo}
    __shared__ unsigned short ldsB[2][2][BN * 32];

    const int tid  = threadIdx.x;
    const int wave = tid >> 6;
    const int lane = tid & 63;
    const int nbn  = N / BN;
    const int mb   = blockIdx.x / nbn;
    const int nb   = blockIdx.x % nbn;

    // staging: slot c: rows (c*4+wave)*16 + lane/4; source chunk inverse-swizzled
    const int row0 = (wave)     * 16 + (lane >> 2);
    const int row1 = (wave + 4) * 16 + (lane >> 2);
    const int koff = (((lane & 3) ^ ((lane >> 3) & 3)) << 3);
    const size_t aoff0 = (size_t)(mb * 128 + row0) * K + koff;
    const size_t aoff1 = (size_t)(mb * 128 + row1) * K + koff;
    const size_t boff0 = (size_t)(nb * BN + row0) * K + koff;
    const size_t boff1 = (size_t)(nb * BN + row1) * K + koff;   // BN==128 only
    const int l0 = wave * 512;          // wave-uniform LDS bases (ushort idx)
    const int l1 = (wave + 4) * 512;

    const int wr = wave >> 1, wc = wave & 1;
    const int fr = lane & 15;
    const int g  = lane >> 4;                    // k-chunk 0..3
    const int ksel = (fr >> 1) & 3;              // read-side swizzle selector

    f32x4 acc[4][NFR];
#pragma unroll
    for (int m = 0; m < 4; ++m)
#pragma unroll
        for (int n = 0; n < NFR; ++n) acc[m][n] = (f32x4){0.f, 0.f, 0.f, 0.f};

    auto STAGE = [&](int bi, int kt) {
        g2l16(Ah + aoff0 + kt, &ldsA[bi][0][l0]);
        g2l16(Ah + aoff1 + kt, &ldsA[bi][0][l1]);
        g2l16(Al + aoff0 + kt, &ldsA[bi][1][l0]);
        g2l16(Al + aoff1 + kt, &ldsA[bi][1][l1]);
        g2l16(Bh + boff0 + kt, &ldsB[bi][0][l0]);
        g2l16(Bl + boff0 + kt, &ldsB[bi][1][l0]);
        if constexpr (BN == 128) {
            g2l16(Bh + boff1 + kt, &ldsB[bi][0][l1]);
            g2l16(Bl + boff1 + kt, &ldsB[bi][1][l1]);
        }
    };

    STAGE(0, 0);
    __syncthreads();                     // drain vmcnt(0): buf0 ready
    int cur = 0;

    for (int kt = 0; kt < K; kt += 32) {
        if (kt + 32 < K) STAGE(cur ^ 1, kt + 32);   // in flight across compute

        const int co = ((g ^ ksel) << 3);           // swizzled chunk offset
        short8v ah[4], al[4], bh[NFR], bl[NFR];
#pragma unroll
        for (int m = 0; m < 4; ++m) {
            const int r = (wr * 64 + m * 16 + fr) * 32 + co;
            ah[m] = *(const short8v*)&ldsA[cur][0][r];
            al[m] = *(const short8v*)&ldsA[cur][1][r];
        }
#pragma unroll
        for (int n = 0; n < NFR; ++n) {
            const int r = (wc * (BN / 2) + n * 16 + fr) * 32 + co;
            bh[n] = *(const short8v*)&ldsB[cur][0][r];
            bl[n] = *(const short8v*)&ldsB[cur][1][r];
        }
        __builtin_amdgcn_s_setprio(1);
#pragma unroll
        for (int m = 0; m < 4; ++m)
#pragma unroll
            for (int n = 0; n < NFR; ++n) {
                acc[m][n] = __builtin_amdgcn_mfma_f32_16x16x32_bf16(
                    ah[m], bh[n], acc[m][n], 0, 0, 0);
                acc[m][n] = __builtin_amdgcn_mfma_f32_16x16x32_bf16(
                    ah[m], bl[n], acc[m][n], 0, 0, 0);
                acc[m][n] = __builtin_amdgcn_mfma_f32_16x16x32_bf16(
                    al[m], bh[n], acc[m][n], 0, 0, 0);
            }
        __builtin_amdgcn_s_setprio(0);

        __syncthreads();   // vmcnt(0)+lgkmcnt(0)+barrier: next buf staged,
        cur ^= 1;          // this buf free for overwrite next iteration
    }

    const int cr = (lane >> 4) * 4;      // C/D: col = lane&15, row = cr + reg
#pragma unroll
    for (int m = 0; m < 4; ++m)
#pragma unroll
        for (int n = 0; n < NFR; ++n) {
#pragma unroll
            for (int r = 0; r < 4; ++r) {
                const int row = mb * 128 + wr * 64 + m * 16 + cr + r;
                const int col = nb * BN + wc * (BN / 2) + n * 16 + fr;
                if constexpr (OUTMODE == 0) {
                    Cf[(size_t)row * N + col] = acc[m][n][r];
                } else {
                    float v = acc[m][n][r];
                    if (col < CEMB) v *= 0.125f;   // pre-scale Q by 1/sqrt(D)
                    unsigned short hb = f2bf_rn(v);
                    Ch[(size_t)row * N + col] = hb;
                    Cl[(size_t)row * N + col] = f2bf_rn(v - bf2f(hb));
                }
            }
        }
}

// ---------- fused attention, split-bf16 MFMA ----------
// R5/R7 structure + per-lane partial l (R8) + setprio around MFMA clusters.
__global__ __launch_bounds__(TB)
void attn_mfma_kernel(const unsigned short* __restrict__ qkvh,
                      const unsigned short* __restrict__ qkvl,
                      unsigned short* __restrict__ yh,
                      unsigned short* __restrict__ yl, int T) {
    __shared__ unsigned short Kh[4096], Kl[4096], VTh[4096], VTl[4096],
                              Ph[4096], Pl[4096];

    const int tid = threadIdx.x;
    const int wv  = tid >> 6, ln = tid & 63;
    const int g   = ln >> 4, fr = ln & 15;
    const int nq  = T >> 6;
    const int qt  = blockIdx.x % nq;
    const int bh  = blockIdx.x / nq;
    const int h   = bh % NHD, b = bh / NHD;
    const int qs  = qt << 6;
    const size_t bT = (size_t)b * T;

    const size_t qbase = (bT + qs + wv * 16 + fr) * C3 + h * DH;
    short8v qfh[2], qfl[2];
    qfh[0] = *(const short8v*)(qkvh + qbase + g * 8);
    qfh[1] = *(const short8v*)(qkvh + qbase + 32 + g * 8);
    qfl[0] = *(const short8v*)(qkvl + qbase + g * 8);
    qfl[1] = *(const short8v*)(qkvl + qbase + 32 + g * 8);

    float mrow[4], lrow[4];
    f32x4 acc_o[4];
#pragma unroll
    for (int r = 0; r < 4; ++r) { mrow[r] = -3.0e38f; lrow[r] = 0.f; }
#pragma unroll
    for (int j = 0; j < 4; ++j) acc_o[j] = (f32x4){0.f, 0.f, 0.f, 0.f};

    int kt_first = 0;
    const int wstart = qs - (WIN - 1);
    if (wstart > 0) kt_first = wstart >> 6;
    const int has_g = (kt_first > 0) ? 1 : 0;
    const int npass = qt - kt_first + 1 + has_g;

    const int srow = tid >> 2;
    const int sc   = tid & 3;
    const int kidx0 = srow * 64 + ((sc * 8)       ^ ((srow & 7) << 3));
    const int kidx1 = srow * 64 + (((sc + 4) * 8) ^ ((srow & 7) << 3));

    short8v kh0, kh1, kl0, kl1, vh0, vh1, vl0, vl1;
    auto load_tile = [&](int k0) {
        const size_t kb = (bT + k0 + srow) * C3 + CEMB + h * DH;
        kh0 = *(const short8v*)(qkvh + kb + sc * 8);
        kh1 = *(const short8v*)(qkvh + kb + (sc + 4) * 8);
        kl0 = *(const short8v*)(qkvl + kb + sc * 8);
        kl1 = *(const short8v*)(qkvl + kb + (sc + 4) * 8);
        const size_t vb = (bT + k0 + srow) * C3 + 2 * CEMB + h * DH + sc * 16;
        vh0 = *(const short8v*)(qkvh + vb);
        vh1 = *(const short8v*)(qkvh + vb + 8);
        vl0 = *(const short8v*)(qkvl + vb);
        vl1 = *(const short8v*)(qkvl + vb + 8);
    };
    auto kt_of = [&](int p) { return (has_g && p == 0) ? 0 : (kt_first + p - has_g); };

    load_tile(kt_of(0) * 64);

    for (int pass = 0; pass < npass; ++pass) {
        const int k0 = kt_of(pass) * 64;

        __syncthreads();
        *(short8v*)&Kh[kidx0] = kh0; *(short8v*)&Kh[kidx1] = kh1;
        *(short8v*)&Kl[kidx0] = kl0; *(short8v*)&Kl[kidx1] = kl1;
#pragma unroll
        for (int e = 0; e < 8; ++e) {
            const int d1 = sc * 16 + e, d2 = sc * 16 + 8 + e;
            const int i1 = d1 * 64 + (srow ^ (((d1 ^ (d1 >> 3)) & 7) << 3));
            const int i2 = d2 * 64 + (srow ^ (((d2 ^ (d2 >> 3)) & 7) << 3));
            VTh[i1] = (unsigned short)vh0[e]; VTh[i2] = (unsigned short)vh1[e];
            VTl[i1] = (unsigned short)vl0[e]; VTl[i2] = (unsigned short)vl1[e];
        }
        __syncthreads();

        if (pass + 1 < npass) load_tile(kt_of(pass + 1) * 64);

        f32x4 sa[4];
#pragma unroll
        for (int j = 0; j < 4; ++j) sa[j] = (f32x4){0.f, 0.f, 0.f, 0.f};
        __builtin_amdgcn_s_setprio(1);
#pragma unroll
        for (int kk = 0; kk < 2; ++kk) {
#pragma unroll
            for (int j = 0; j < 4; ++j) {
                const int krow = j * 16 + fr;
                const int off  = (kk * 32 + g * 8) ^ ((krow & 7) << 3);
                short8v bhf = *(const short8v*)&Kh[krow * 64 + off];
                short8v blf = *(const short8v*)&Kl[krow * 64 + off];
                sa[j] = __builtin_amdgcn_mfma_f32_16x16x32_bf16(qfh[kk], bhf, sa[j], 0, 0, 0);
                sa[j] = __builtin_amdgcn_mfma_f32_16x16x32_bf16(qfh[kk], blf, sa[j], 0, 0, 0);
                sa[j] = __builtin_amdgcn_mfma_f32_16x16x32_bf16(qfl[kk], bhf, sa[j], 0, 0, 0);
            }
        }
        __builtin_amdgcn_s_setprio(0);

#pragma unroll
        for (int r = 0; r < 4; ++r) {
            const int qloc = wv * 16 + g * 4 + r;
            const int qi   = qs + qloc;
            const int wlo  = qi - (WIN - 1);
            float mx = mrow[r];
            float s[4];
#pragma unroll
            for (int j = 0; j < 4; ++j) {
                const int kj = k0 + j * 16 + fr;
                const bool valid = (kj <= qi) && ((kj >= wlo) || (kj < NGLB));
                s[j] = valid ? sa[j][r] : -3.0e38f;
                mx = fmaxf(mx, s[j]);
            }
#pragma unroll
            for (int off = 1; off < 16; off <<= 1)
                mx = fmaxf(mx, __shfl_xor(mx, off, 64));
            const float alpha = __expf(mrow[r] - mx);
            float rsum = 0.f;
            unsigned short phv[4], plv[4];
#pragma unroll
            for (int j = 0; j < 4; ++j) {
                const float p = (s[j] > -1.0e38f) ? __expf(s[j] - mx) : 0.f;
                rsum += p;
                const unsigned short hb = f2bf_rn(p);
                phv[j] = hb; plv[j] = f2bf_rn(p - bf2f(hb));
            }
            lrow[r] = lrow[r] * alpha + rsum;    // per-lane partial (alpha uniform)
            mrow[r] = mx;
#pragma unroll
            for (int j = 0; j < 4; ++j) {
                acc_o[j][r] *= alpha;
                const int key = j * 16 + fr;
                const int idx = qloc * 64 + (key ^ ((qloc & 7) << 3));
                Ph[idx] = phv[j]; Pl[idx] = plv[j];
            }
        }

        __builtin_amdgcn_s_setprio(1);
#pragma unroll
        for (int kk = 0; kk < 2; ++kk) {
            const int qloc = wv * 16 + fr;
            const int poff = (kk * 32 + g * 8) ^ ((qloc & 7) << 3);
            short8v pah = *(const short8v*)&Ph[qloc * 64 + poff];
            short8v pal = *(const short8v*)&Pl[qloc * 64 + poff];
#pragma unroll
            for (int j = 0; j < 4; ++j) {
                const int d   = j * 16 + fr;
                const int voff = (kk * 32 + g * 8) ^ (((d ^ (d >> 3)) & 7) << 3);
                short8v vfh = *(const short8v*)&VTh[d * 64 + voff];
                short8v vfl = *(const short8v*)&VTl[d * 64 + voff];
                acc_o[j] = __builtin_amdgcn_mfma_f32_16x16x32_bf16(pah, vfh, acc_o[j], 0, 0, 0);
                acc_o[j] = __builtin_amdgcn_mfma_f32_16x16x32_bf16(pah, vfl, acc_o[j], 0, 0, 0);
                acc_o[j] = __builtin_amdgcn_mfma_f32_16x16x32_bf16(pal, vfh, acc_o[j], 0, 0, 0);
            }
        }
        __builtin_amdgcn_s_setprio(0);
    }

    // epilogue: deferred row-sum reduce (16-lane groups), normalize, write y
    float inv[4];
#pragma unroll
    for (int r = 0; r < 4; ++r) {
        float s = lrow[r];
#pragma unroll
        for (int off = 1; off < 16; off <<= 1)
            s += __shfl_xor(s, off, 64);
        inv[r] = 1.0f / s;
    }
#pragma unroll
    for (int j = 0; j < 4; ++j)
#pragma unroll
        for (int r = 0; r < 4; ++r) {
            const float o = acc_o[j][r] * inv[r];
            const size_t yi = (bT + qs + wv * 16 + g * 4 + r) * (size_t)CEMB
                            + h * DH + j * 16 + fr;
            const unsigned short hb = f2bf_rn(o);
            yh[yi] = hb; yl[yi] = f2bf_rn(o - bf2f(hb));
        }
}

// ===================== launcher =====================
extern "C" void kernel_launch(void* const* d_in, const int* in_sizes, int n_in,
                              void* d_out, int out_size, void* d_ws, size_t ws_size,
                              hipStream_t stream) {
    const float* x      = (const float*)d_in[0];
    const float* w_attn = (const float*)d_in[1];
    const float* w_proj = (const float*)d_in[2];
    float* out = (float*)d_out;

    const int T = 2048;
    const int B = in_sizes[0] / (T * CEMB);
    const int M = B * T;

    unsigned short* qkvh = (unsigned short*)d_ws;          // [M][3C]
    unsigned short* qkvl = qkvh + (size_t)M * C3;
    unsigned short* yh   = qkvl + (size_t)M * C3;          // [M][C]
    unsigned short* yl   = yh   + (size_t)M * CEMB;
    unsigned short* xh   = yl   + (size_t)M * CEMB;
    unsigned short* xl   = xh   + (size_t)M * CEMB;
    unsigned short* wah  = xl   + (size_t)M * CEMB;
    unsigned short* wal  = wah  + (size_t)C3 * CEMB;
    unsigned short* wph  = wal  + (size_t)C3 * CEMB;
    unsigned short* wpl  = wph  + (size_t)CEMB * CEMB;

    const int n8x = M * CEMB / 8;
    const int n8a = C3 * CEMB / 8;
    const int n8p = CEMB * CEMB / 8;
    split3_kernel<<<2048, TB, 0, stream>>>(x, w_attn, w_proj,
                                           xh, xl, wah, wal, wph, wpl,
                                           n8x, n8a, n8p);

    gemm_split_mfma_kernel<1, 128><<<dim3((M / 128) * (C3 / 128)), dim3(TB), 0, stream>>>(
        xh, xl, wah, wal, nullptr, qkvh, qkvl, M, C3, CEMB);

    attn_mfma_kernel<<<dim3(B * NHD * (T / 64)), dim3(TB), 0, stream>>>(
        qkvh, qkvl, yh, yl, T);

    gemm_split_mfma_kernel<0, 64><<<dim3((M / 128) * (CEMB / 64)), dim3(TB), 0, stream>>>(
        yh, yl, wph, wpl, out, nullptr, nullptr, M, CEMB, CEMB);
}

// Round 11
// 251.014 us; speedup vs baseline: 1.0469x; 1.0269x over previous
//
#include <hip/hip_runtime.h>

// LocalGlobalCausalSelfAttention — R11:
//  * setprio REMOVED everywhere (R10 A/B: g1 90.2->100.3 µs, MfmaUtil
//    35.8->31.3 — T5 is null-to-negative on lockstep 2-phase structures,
//    replicating m190; attn has the same structure).
//  * XCD-chunked block swizzle on both GEMMs (T1): consecutive nb blocks
//    share an A-panel; default round-robin spreads them over 8 XCD L2s
//    (FETCH 80MB vs 29MB ideal). swz=(bid&7)*(nwg/8)+bid/8, bijective
//    (nwg=768,512 both %8==0).
//  * Keeps: BN=64 GEMM2 tile (3 blocks/CU), per-lane partial l in attn.

#define NHD   16
#define CEMB  1024
#define C3    3072
#define DH    64
#define WIN   256
#define NGLB  4
#define TB    256

typedef __attribute__((ext_vector_type(8))) short  short8v;
typedef __attribute__((ext_vector_type(4))) float  f32x4;
typedef __attribute__((ext_vector_type(8))) unsigned short ushort8v;

__device__ __forceinline__ unsigned short f2bf_rn(float f) {
    unsigned int u = __float_as_uint(f);
    u += 0x7fffu + ((u >> 16) & 1u);
    return (unsigned short)(u >> 16);
}
__device__ __forceinline__ float bf2f(unsigned short h) {
    return __uint_as_float(((unsigned int)h) << 16);
}

// ---------- fused fp32 -> (bf16 hi, bf16 lo) split for x, w_attn, w_proj ----------
__global__ __launch_bounds__(TB)
void split3_kernel(const float* __restrict__ x, const float* __restrict__ wa,
                   const float* __restrict__ wp,
                   unsigned short* __restrict__ xh, unsigned short* __restrict__ xl,
                   unsigned short* __restrict__ wah, unsigned short* __restrict__ wal,
                   unsigned short* __restrict__ wph, unsigned short* __restrict__ wpl,
                   int n8x, int n8a, int n8p) {
    const int total = n8x + n8a + n8p;
    for (int i = blockIdx.x * blockDim.x + threadIdx.x; i < total;
         i += gridDim.x * blockDim.x) {
        const float* src; unsigned short *ph, *pl; int j;
        if (i < n8x)            { src = x;  ph = xh;  pl = xl;  j = i; }
        else if (i < n8x + n8a) { src = wa; ph = wah; pl = wal; j = i - n8x; }
        else                    { src = wp; ph = wph; pl = wpl; j = i - n8x - n8a; }
        float4 v0 = ((const float4*)src)[2 * j];
        float4 v1 = ((const float4*)src)[2 * j + 1];
        float f[8] = {v0.x, v0.y, v0.z, v0.w, v1.x, v1.y, v1.z, v1.w};
        ushort8v h, l;
#pragma unroll
        for (int e = 0; e < 8; ++e) {
            unsigned short hb = f2bf_rn(f[e]);
            h[e] = hb;
            l[e] = f2bf_rn(f[e] - bf2f(hb));
        }
        *(ushort8v*)&ph[(size_t)j * 8] = h;
        *(ushort8v*)&pl[(size_t)j * 8] = l;
    }
}

// ---------- split-bf16 MFMA GEMM: C[M,N] = A[M,K] * B[N,K]^T ----------
// 128xBN tile, BK=32, 4 waves (2x2), mfma_f32_16x16x32_bf16, 3-term split.
// BN=128: 4x4 frags, 48 MFMA/K-step (R7 config: 90µs, 0 conflicts).
// BN=64: 4x2 frags, 48KB LDS -> 3 blocks/CU (proj GEMM, 512 blocks).
// 2-phase dbuf; LDS 16B-chunk swizzle slot = c ^ ((row>>1)&3) (rule #21:
// linear gload_lds dest + inverse-permuted global source + same XOR on read).
// XCD-chunked bid swizzle: requires gridDim.x % 8 == 0 (launcher guarantees).
__device__ __forceinline__ void g2l16(const void* g, void* l) {
    __builtin_amdgcn_global_load_lds(
        (const __attribute__((address_space(1))) void*)g,
        (__attribute__((address_space(3))) void*)l, 16, 0, 0);
}

// OUTMODE 0: f32 C.  OUTMODE 1: hi/lo bf16 C, cols < CEMB scaled by 1/8 (Q).
template<int OUTMODE, int BN>
__global__ __launch_bounds__(TB)
void gemm_split_mfma_kernel(const unsigned short* __restrict__ Ah,
                            const unsigned short* __restrict__ Al,
                            const unsigned short* __restrict__ Bh,
                            const unsigned short* __restrict__ Bl,
                            float* __restrict__ Cf,
                            unsigned short* __restrict__ Ch,
                            unsigned short* __restrict__ Cl,
                            int M, int N, int K) {
    constexpr int NFR = BN / 32;                      // n-frags per wave: 4 or 2
    __shared__ unsigned short ldsA[2][2][128 * 32];   // dbuf x {hi,lo}
    __shared__ unsigned short ldsB[2][2][BN * 32];

    const int tid  = threadIdx.x;
    const int wave = tid >> 6;
    const int lane = tid & 63;

    // XCD-chunked swizzle: XCD r (= bid%8 by dispatch round-robin) gets the
    // contiguous work chunk [r*nwg/8, (r+1)*nwg/8) -> A-panels stay in its L2.
    const int nwg  = gridDim.x;
    const int bid  = (blockIdx.x & 7) * (nwg >> 3) + (blockIdx.x >> 3);
    const int nbn  = N / BN;
    const int mb   = bid / nbn;
    const int nb   = bid % nbn;

    // staging: slot c: rows (c*4+wave)*16 + lane/4; source chunk inverse-swizzled
    const int row0 = (wave)     * 16 + (lane >> 2);
    const int row1 = (wave + 4) * 16 + (lane >> 2);
    const int koff = (((lane & 3) ^ ((lane >> 3) & 3)) << 3);
    const size_t aoff0 = (size_t)(mb * 128 + row0) * K + koff;
    const size_t aoff1 = (size_t)(mb * 128 + row1) * K + koff;
    const size_t boff0 = (size_t)(nb * BN + row0) * K + koff;
    const size_t boff1 = (size_t)(nb * BN + row1) * K + koff;   // BN==128 only
    const int l0 = wave * 512;          // wave-uniform LDS bases (ushort idx)
    const int l1 = (wave + 4) * 512;

    const int wr = wave >> 1, wc = wave & 1;
    const int fr = lane & 15;
    const int g  = lane >> 4;                    // k-chunk 0..3
    const int ksel = (fr >> 1) & 3;              // read-side swizzle selector

    f32x4 acc[4][NFR];
#pragma unroll
    for (int m = 0; m < 4; ++m)
#pragma unroll
        for (int n = 0; n < NFR; ++n) acc[m][n] = (f32x4){0.f, 0.f, 0.f, 0.f};

    auto STAGE = [&](int bi, int kt) {
        g2l16(Ah + aoff0 + kt, &ldsA[bi][0][l0]);
        g2l16(Ah + aoff1 + kt, &ldsA[bi][0][l1]);
        g2l16(Al + aoff0 + kt, &ldsA[bi][1][l0]);
        g2l16(Al + aoff1 + kt, &ldsA[bi][1][l1]);
        g2l16(Bh + boff0 + kt, &ldsB[bi][0][l0]);
        g2l16(Bl + boff0 + kt, &ldsB[bi][1][l0]);
        if constexpr (BN == 128) {
            g2l16(Bh + boff1 + kt, &ldsB[bi][0][l1]);
            g2l16(Bl + boff1 + kt, &ldsB[bi][1][l1]);
        }
    };

    STAGE(0, 0);
    __syncthreads();                     // drain vmcnt(0): buf0 ready
    int cur = 0;

    for (int kt = 0; kt < K; kt += 32) {
        if (kt + 32 < K) STAGE(cur ^ 1, kt + 32);   // in flight across compute

        const int co = ((g ^ ksel) << 3);           // swizzled chunk offset
        short8v ah[4], al[4], bh[NFR], bl[NFR];
#pragma unroll
        for (int m = 0; m < 4; ++m) {
            const int r = (wr * 64 + m * 16 + fr) * 32 + co;
            ah[m] = *(const short8v*)&ldsA[cur][0][r];
            al[m] = *(const short8v*)&ldsA[cur][1][r];
        }
#pragma unroll
        for (int n = 0; n < NFR; ++n) {
            const int r = (wc * (BN / 2) + n * 16 + fr) * 32 + co;
            bh[n] = *(const short8v*)&ldsB[cur][0][r];
            bl[n] = *(const short8v*)&ldsB[cur][1][r];
        }
#pragma unroll
        for (int m = 0; m < 4; ++m)
#pragma unroll
            for (int n = 0; n < NFR; ++n) {
                acc[m][n] = __builtin_amdgcn_mfma_f32_16x16x32_bf16(
                    ah[m], bh[n], acc[m][n], 0, 0, 0);
                acc[m][n] = __builtin_amdgcn_mfma_f32_16x16x32_bf16(
                    ah[m], bl[n], acc[m][n], 0, 0, 0);
                acc[m][n] = __builtin_amdgcn_mfma_f32_16x16x32_bf16(
                    al[m], bh[n], acc[m][n], 0, 0, 0);
            }

        __syncthreads();   // vmcnt(0)+lgkmcnt(0)+barrier: next buf staged,
        cur ^= 1;          // this buf free for overwrite next iteration
    }

    const int cr = (lane >> 4) * 4;      // C/D: col = lane&15, row = cr + reg
#pragma unroll
    for (int m = 0; m < 4; ++m)
#pragma unroll
        for (int n = 0; n < NFR; ++n) {
#pragma unroll
            for (int r = 0; r < 4; ++r) {
                const int row = mb * 128 + wr * 64 + m * 16 + cr + r;
                const int col = nb * BN + wc * (BN / 2) + n * 16 + fr;
                if constexpr (OUTMODE == 0) {
                    Cf[(size_t)row * N + col] = acc[m][n][r];
                } else {
                    float v = acc[m][n][r];
                    if (col < CEMB) v *= 0.125f;   // pre-scale Q by 1/sqrt(D)
                    unsigned short hb = f2bf_rn(v);
                    Ch[(size_t)row * N + col] = hb;
                    Cl[(size_t)row * N + col] = f2bf_rn(v - bf2f(hb));
                }
            }
        }
}

// ---------- fused attention, split-bf16 MFMA ----------
// R7 structure + per-lane partial l (no setprio — lockstep structure).
__global__ __launch_bounds__(TB)
void attn_mfma_kernel(const unsigned short* __restrict__ qkvh,
                      const unsigned short* __restrict__ qkvl,
                      unsigned short* __restrict__ yh,
                      unsigned short* __restrict__ yl, int T) {
    __shared__ unsigned short Kh[4096], Kl[4096], VTh[4096], VTl[4096],
                              Ph[4096], Pl[4096];

    const int tid = threadIdx.x;
    const int wv  = tid >> 6, ln = tid & 63;
    const int g   = ln >> 4, fr = ln & 15;
    const int nq  = T >> 6;
    const int qt  = blockIdx.x % nq;
    const int bh  = blockIdx.x / nq;
    const int h   = bh % NHD, b = bh / NHD;
    const int qs  = qt << 6;
    const size_t bT = (size_t)b * T;

    const size_t qbase = (bT + qs + wv * 16 + fr) * C3 + h * DH;
    short8v qfh[2], qfl[2];
    qfh[0] = *(const short8v*)(qkvh + qbase + g * 8);
    qfh[1] = *(const short8v*)(qkvh + qbase + 32 + g * 8);
    qfl[0] = *(const short8v*)(qkvl + qbase + g * 8);
    qfl[1] = *(const short8v*)(qkvl + qbase + 32 + g * 8);

    float mrow[4], lrow[4];
    f32x4 acc_o[4];
#pragma unroll
    for (int r = 0; r < 4; ++r) { mrow[r] = -3.0e38f; lrow[r] = 0.f; }
#pragma unroll
    for (int j = 0; j < 4; ++j) acc_o[j] = (f32x4){0.f, 0.f, 0.f, 0.f};

    int kt_first = 0;
    const int wstart = qs - (WIN - 1);
    if (wstart > 0) kt_first = wstart >> 6;
    const int has_g = (kt_first > 0) ? 1 : 0;
    const int npass = qt - kt_first + 1 + has_g;

    const int srow = tid >> 2;
    const int sc   = tid & 3;
    const int kidx0 = srow * 64 + ((sc * 8)       ^ ((srow & 7) << 3));
    const int kidx1 = srow * 64 + (((sc + 4) * 8) ^ ((srow & 7) << 3));

    short8v kh0, kh1, kl0, kl1, vh0, vh1, vl0, vl1;
    auto load_tile = [&](int k0) {
        const size_t kb = (bT + k0 + srow) * C3 + CEMB + h * DH;
        kh0 = *(const short8v*)(qkvh + kb + sc * 8);
        kh1 = *(const short8v*)(qkvh + kb + (sc + 4) * 8);
        kl0 = *(const short8v*)(qkvl + kb + sc * 8);
        kl1 = *(const short8v*)(qkvl + kb + (sc + 4) * 8);
        const size_t vb = (bT + k0 + srow) * C3 + 2 * CEMB + h * DH + sc * 16;
        vh0 = *(const short8v*)(qkvh + vb);
        vh1 = *(const short8v*)(qkvh + vb + 8);
        vl0 = *(const short8v*)(qkvl + vb);
        vl1 = *(const short8v*)(qkvl + vb + 8);
    };
    auto kt_of = [&](int p) { return (has_g && p == 0) ? 0 : (kt_first + p - has_g); };

    load_tile(kt_of(0) * 64);

    for (int pass = 0; pass < npass; ++pass) {
        const int k0 = kt_of(pass) * 64;

        __syncthreads();
        *(short8v*)&Kh[kidx0] = kh0; *(short8v*)&Kh[kidx1] = kh1;
        *(short8v*)&Kl[kidx0] = kl0; *(short8v*)&Kl[kidx1] = kl1;
#pragma unroll
        for (int e = 0; e < 8; ++e) {
            const int d1 = sc * 16 + e, d2 = sc * 16 + 8 + e;
            const int i1 = d1 * 64 + (srow ^ (((d1 ^ (d1 >> 3)) & 7) << 3));
            const int i2 = d2 * 64 + (srow ^ (((d2 ^ (d2 >> 3)) & 7) << 3));
            VTh[i1] = (unsigned short)vh0[e]; VTh[i2] = (unsigned short)vh1[e];
            VTl[i1] = (unsigned short)vl0[e]; VTl[i2] = (unsigned short)vl1[e];
        }
        __syncthreads();

        if (pass + 1 < npass) load_tile(kt_of(pass + 1) * 64);

        f32x4 sa[4];
#pragma unroll
        for (int j = 0; j < 4; ++j) sa[j] = (f32x4){0.f, 0.f, 0.f, 0.f};
#pragma unroll
        for (int kk = 0; kk < 2; ++kk) {
#pragma unroll
            for (int j = 0; j < 4; ++j) {
                const int krow = j * 16 + fr;
                const int off  = (kk * 32 + g * 8) ^ ((krow & 7) << 3);
                short8v bhf = *(const short8v*)&Kh[krow * 64 + off];
                short8v blf = *(const short8v*)&Kl[krow * 64 + off];
                sa[j] = __builtin_amdgcn_mfma_f32_16x16x32_bf16(qfh[kk], bhf, sa[j], 0, 0, 0);
                sa[j] = __builtin_amdgcn_mfma_f32_16x16x32_bf16(qfh[kk], blf, sa[j], 0, 0, 0);
                sa[j] = __builtin_amdgcn_mfma_f32_16x16x32_bf16(qfl[kk], bhf, sa[j], 0, 0, 0);
            }
        }

#pragma unroll
        for (int r = 0; r < 4; ++r) {
            const int qloc = wv * 16 + g * 4 + r;
            const int qi   = qs + qloc;
            const int wlo  = qi - (WIN - 1);
            float mx = mrow[r];
            float s[4];
#pragma unroll
            for (int j = 0; j < 4; ++j) {
                const int kj = k0 + j * 16 + fr;
                const bool valid = (kj <= qi) && ((kj >= wlo) || (kj < NGLB));
                s[j] = valid ? sa[j][r] : -3.0e38f;
                mx = fmaxf(mx, s[j]);
            }
#pragma unroll
            for (int off = 1; off < 16; off <<= 1)
                mx = fmaxf(mx, __shfl_xor(mx, off, 64));
            const float alpha = __expf(mrow[r] - mx);
            float rsum = 0.f;
            unsigned short phv[4], plv[4];
#pragma unroll
            for (int j = 0; j < 4; ++j) {
                const float p = (s[j] > -1.0e38f) ? __expf(s[j] - mx) : 0.f;
                rsum += p;
                const unsigned short hb = f2bf_rn(p);
                phv[j] = hb; plv[j] = f2bf_rn(p - bf2f(hb));
            }
            lrow[r] = lrow[r] * alpha + rsum;    // per-lane partial (alpha uniform)
            mrow[r] = mx;
#pragma unroll
            for (int j = 0; j < 4; ++j) {
                acc_o[j][r] *= alpha;
                const int key = j * 16 + fr;
                const int idx = qloc * 64 + (key ^ ((qloc & 7) << 3));
                Ph[idx] = phv[j]; Pl[idx] = plv[j];
            }
        }

#pragma unroll
        for (int kk = 0; kk < 2; ++kk) {
            const int qloc = wv * 16 + fr;
            const int poff = (kk * 32 + g * 8) ^ ((qloc & 7) << 3);
            short8v pah = *(const short8v*)&Ph[qloc * 64 + poff];
            short8v pal = *(const short8v*)&Pl[qloc * 64 + poff];
#pragma unroll
            for (int j = 0; j < 4; ++j) {
                const int d   = j * 16 + fr;
                const int voff = (kk * 32 + g * 8) ^ (((d ^ (d >> 3)) & 7) << 3);
                short8v vfh = *(const short8v*)&VTh[d * 64 + voff];
                short8v vfl = *(const short8v*)&VTl[d * 64 + voff];
                acc_o[j] = __builtin_amdgcn_mfma_f32_16x16x32_bf16(pah, vfh, acc_o[j], 0, 0, 0);
                acc_o[j] = __builtin_amdgcn_mfma_f32_16x16x32_bf16(pah, vfl, acc_o[j], 0, 0, 0);
                acc_o[j] = __builtin_amdgcn_mfma_f32_16x16x32_bf16(pal, vfh, acc_o[j], 0, 0, 0);
            }
        }
    }

    // epilogue: deferred row-sum reduce (16-lane groups), normalize, write y
    float inv[4];
#pragma unroll
    for (int r = 0; r < 4; ++r) {
        float s = lrow[r];
#pragma unroll
        for (int off = 1; off < 16; off <<= 1)
            s += __shfl_xor(s, off, 64);
        inv[r] = 1.0f / s;
    }
#pragma unroll
    for (int j = 0; j < 4; ++j)
#pragma unroll
        for (int r = 0; r < 4; ++r) {
            const float o = acc_o[j][r] * inv[r];
            const size_t yi = (bT + qs + wv * 16 + g * 4 + r) * (size_t)CEMB
                            + h * DH + j * 16 + fr;
            const unsigned short hb = f2bf_rn(o);
            yh[yi] = hb; yl[yi] = f2bf_rn(o - bf2f(hb));
        }
}

// ===================== launcher =====================
extern "C" void kernel_launch(void* const* d_in, const int* in_sizes, int n_in,
                              void* d_out, int out_size, void* d_ws, size_t ws_size,
                              hipStream_t stream) {
    const float* x      = (const float*)d_in[0];
    const float* w_attn = (const float*)d_in[1];
    const float* w_proj = (const float*)d_in[2];
    float* out = (float*)d_out;

    const int T = 2048;
    const int B = in_sizes[0] / (T * CEMB);
    const int M = B * T;

    unsigned short* qkvh = (unsigned short*)d_ws;          // [M][3C]
    unsigned short* qkvl = qkvh + (size_t)M * C3;
    unsigned short* yh   = qkvl + (size_t)M * C3;          // [M][C]
    unsigned short* yl   = yh   + (size_t)M * CEMB;
    unsigned short* xh   = yl   + (size_t)M * CEMB;
    unsigned short* xl   = xh   + (size_t)M * CEMB;
    unsigned short* wah  = xl   + (size_t)M * CEMB;
    unsigned short* wal  = wah  + (size_t)C3 * CEMB;
    unsigned short* wph  = wal  + (size_t)C3 * CEMB;
    unsigned short* wpl  = wph  + (size_t)CEMB * CEMB;

    const int n8x = M * CEMB / 8;
    const int n8a = C3 * CEMB / 8;
    const int n8p = CEMB * CEMB / 8;
    split3_kernel<<<2048, TB, 0, stream>>>(x, w_attn, w_proj,
                                           xh, xl, wah, wal, wph, wpl,
                                           n8x, n8a, n8p);

    gemm_split_mfma_kernel<1, 128><<<dim3((M / 128) * (C3 / 128)), dim3(TB), 0, stream>>>(
        xh, xl, wah, wal, nullptr, qkvh, qkvl, M, C3, CEMB);   // 768 blocks (%8==0)

    attn_mfma_kernel<<<dim3(B * NHD * (T / 64)), dim3(TB), 0, stream>>>(
        qkvh, qkvl, yh, yl, T);

    gemm_split_mfma_kernel<0, 64><<<dim3((M / 128) * (CEMB / 64)), dim3(TB), 0, stream>>>(
        yh, yl, wph, wpl, out, nullptr, nullptr, M, CEMB, CEMB);  // 512 blocks (%8==0)
}